// Round 1
// baseline (1738.064 us; speedup 1.0000x reference)
//
#include <hip/hip_runtime.h>

#define N_USERS    50000
#define N_ENTITIES 100000
#define EMB        64
#define N_EDGES    2000000
#define NNZ        2000000
#define SLOPE      0.2f

// ---- bucket geometry: 128 rows per bucket on BOTH sides --------------------
#define RSHIFT  7
#define BROWS   128
#define NBK     782                 // ceil(100000/128)
#define NBU     391                 // ceil(50000/128)
#define CHUNK   8192                // edges per partition block
#define EPT     (CHUNK / 512)       // 16 edges per thread in hist/scatter
#define PB      ((N_EDGES + CHUNK - 1) / CHUNK)      // 245

// ============================================================================
// Pass 0: fused bucket histograms (LDS-privatized)
// ============================================================================
__global__ __launch_bounds__(512) void hist_both(const int* __restrict__ head,
                                                 const int* __restrict__ urows,
                                                 int* __restrict__ kgOffs,
                                                 int* __restrict__ uOffs) {
    __shared__ int lhk[NBK];
    __shared__ int lhu[NBU];
    int tid = threadIdx.x;
    for (int t = tid; t < NBK; t += 512) lhk[t] = 0;
    for (int t = tid; t < NBU; t += 512) lhu[t] = 0;
    __syncthreads();
    int base = blockIdx.x * CHUNK;
#pragma unroll 4
    for (int j = 0; j < EPT; ++j) {
        int i = base + j * 512 + tid;
        if (i < N_EDGES) atomicAdd(&lhk[head[i] >> RSHIFT], 1);
        if (i < NNZ)     atomicAdd(&lhu[urows[i] >> RSHIFT], 1);
    }
    __syncthreads();
    for (int t = tid; t < NBK; t += 512) { int c = lhk[t]; if (c) atomicAdd(&kgOffs[t], c); }
    for (int t = tid; t < NBU; t += 512) { int c = lhu[t]; if (c) atomicAdd(&uOffs[t], c); }
}

// ============================================================================
// Pass 1: exclusive scan of both bucket histograms (grid = 2 blocks of 1024)
// ============================================================================
__global__ __launch_bounds__(1024) void scan_both(int* __restrict__ kgOffs,
                                                  int* __restrict__ kgCur,
                                                  int* __restrict__ uOffs,
                                                  int* __restrict__ uCur) {
    __shared__ int tsum[1024];
    int n     = (blockIdx.x == 0) ? NBK : NBU;
    int* offs = (blockIdx.x == 0) ? kgOffs : uOffs;
    int* cur  = (blockIdx.x == 0) ? kgCur  : uCur;
    int tid = threadIdx.x;
    int v = (tid < n) ? offs[tid] : 0;
    tsum[tid] = v;
    __syncthreads();
    for (int off = 1; off < 1024; off <<= 1) {
        int t = (tid >= off) ? tsum[tid - off] : 0;
        __syncthreads();
        tsum[tid] += t;
        __syncthreads();
    }
    if (tid < n) { int e = tsum[tid] - v; offs[tid] = e; cur[tid] = e; }
    if (tid == n - 1) offs[n] = tsum[tid];
}

// ============================================================================
// Small dense math (one wave's worth of work): latent_new, P = W1^T*lat1^T,
// c = b1*lat1^T.  Written as a device function so it can be fused into
// scatter_both (extra block) -- all threads of the calling block must enter
// (barriers are executed by everyone; only tid<64 compute).
// ============================================================================
__device__ void small_dense_body(int l,
                                 const float* __restrict__ latent_emb,
                                 const float* __restrict__ weight,
                                 const float* __restrict__ W_weight_att,
                                 const float* __restrict__ b_weight_att,
                                 const float* __restrict__ W1,
                                 const float* __restrict__ b1,
                                 const float* __restrict__ W2,
                                 const float* __restrict__ b2,
                                 float* __restrict__ P_out,
                                 float* __restrict__ c_out,
                                 float* __restrict__ latent_new_out) {
    __shared__ float lat1[8 * 64];
    __shared__ float lat2[8 * 64];
    __shared__ float wl2[16 * 64];
    __shared__ float srp[8 * 16];
    __shared__ float soft[8 * 16];

    if (l < 64) {
        for (int f = 0; f < 8; ++f) {
            float a1 = b1[l], a2 = b2[l];
            for (int k = 0; k < 64; ++k) {
                float le = latent_emb[f * 64 + k];
                a1 += le * W1[l * 64 + k];
                a2 += le * W2[l * 64 + k];
            }
            lat1[f * 64 + l] = a1;
            lat2[f * 64 + l] = a2;
        }
        for (int r = 0; r < 16; ++r) {
            float a = b2[l];
            for (int k = 0; k < 64; ++k) a += weight[r * 64 + k] * W2[l * 64 + k];
            wl2[r * 64 + l] = a;
        }
    }
    __syncthreads();

    if (l < 64) {
        for (int f = 0; f < 8; ++f) {
            float p = 0.f;
            for (int d = 0; d < 64; ++d) p += W1[d * 64 + l] * lat1[f * 64 + d];
            P_out[l * 8 + f] = p;
        }
        if (l < 8) {
            float cc = 0.f;
            for (int d = 0; d < 64; ++d) cc += b1[d] * lat1[l * 64 + d];
            c_out[l] = cc;
        }
        for (int idx = l; idx < 128; idx += 64) {
            int f = idx >> 4, r = idx & 15;
            float a = 0.f;
            for (int d = 0; d < 64; ++d) a += lat2[f * 64 + d] * wl2[r * 64 + d];
            srp[idx] = a;
        }
    }
    __syncthreads();

    if (l < 8) {
        int f = l;
        float att[16];
        float mx = -1e30f;
        for (int k = 0; k < 16; ++k) {
            float a = b_weight_att[k];
            for (int j = 0; j < 16; ++j) a += srp[f * 16 + j] * W_weight_att[k * 16 + j];
            a = a > 0.f ? a : SLOPE * a;
            att[k] = a;
            mx = fmaxf(mx, a);
        }
        float s = 0.f;
        for (int k = 0; k < 16; ++k) { att[k] = expf(att[k] - mx); s += att[k]; }
        float inv = 1.f / s;
        for (int k = 0; k < 16; ++k) soft[f * 16 + k] = att[k] * inv;
    }
    __syncthreads();

    if (l < 64) {
        for (int f = 0; f < 8; ++f) {
            float a = 0.f;
            for (int r = 0; r < 16; ++r) a += soft[f * 16 + r] * weight[r * 64 + l];
            latent_new_out[f * 64 + l] = a;
        }
    }
}

__global__ void small_dense(const float* __restrict__ latent_emb,
                            const float* __restrict__ weight,
                            const float* __restrict__ W_weight_att,
                            const float* __restrict__ b_weight_att,
                            const float* __restrict__ W1,
                            const float* __restrict__ b1,
                            const float* __restrict__ W2,
                            const float* __restrict__ b2,
                            float* __restrict__ P_out,
                            float* __restrict__ c_out,
                            float* __restrict__ latent_new_out) {
    small_dense_body(threadIdx.x, latent_emb, weight, W_weight_att, b_weight_att,
                     W1, b1, W2, b2, P_out, c_out, latent_new_out);
}

// ============================================================================
// Pass 2 (merged): bucket partition with block-local reservation.
// blocks [0,PB) handle kg edges; [PB,2*PB) handle user nnz;
// block 2*PB runs the small dense math (hides its serial latency).
// kg payload: tail(0..16) | type-1 (17..20) | rowlow (21..27)
// user payload: int2 { col(0..16) | rowlow(17..23), val_bits }
// ============================================================================
__global__ __launch_bounds__(512) void scatter_both(const int* __restrict__ head,
                                                    const int* __restrict__ tail,
                                                    const int* __restrict__ etype,
                                                    int* __restrict__ kgCur,
                                                    int* __restrict__ kgPay,
                                                    const int* __restrict__ urows,
                                                    const int* __restrict__ ucols,
                                                    const float* __restrict__ uvals,
                                                    int* __restrict__ uCur,
                                                    int2* __restrict__ uPay,
                                                    const float* __restrict__ latent_emb,
                                                    const float* __restrict__ weight,
                                                    const float* __restrict__ W_weight_att,
                                                    const float* __restrict__ b_weight_att,
                                                    const float* __restrict__ W1,
                                                    const float* __restrict__ b1,
                                                    const float* __restrict__ W2,
                                                    const float* __restrict__ b2,
                                                    float* __restrict__ Pbuf,
                                                    float* __restrict__ cbuf,
                                                    float* __restrict__ lat_out) {
    if (blockIdx.x == 2 * PB) {
        small_dense_body(threadIdx.x, latent_emb, weight, W_weight_att,
                         b_weight_att, W1, b1, W2, b2, Pbuf, cbuf, lat_out);
        return;
    }

    __shared__ int lh[NBK];
    __shared__ int lb[NBK];
    int tid = threadIdx.x;
    bool isKg = blockIdx.x < PB;
    int base = (isKg ? blockIdx.x : blockIdx.x - PB) * CHUNK;
    int nb   = isKg ? NBK : NBU;
    int nTot = isKg ? N_EDGES : NNZ;
    const int* src = isKg ? head : urows;
    int* cur = isKg ? kgCur : uCur;

    for (int t = tid; t < NBK; t += 512) lh[t] = 0;
    __syncthreads();

    int hreg[EPT];                       // register-staged keys (read once)
#pragma unroll
    for (int j = 0; j < EPT; ++j) {
        int i = base + j * 512 + tid;
        int h = (i < nTot) ? src[i] : -1;
        hreg[j] = h;
        if (h >= 0) atomicAdd(&lh[h >> RSHIFT], 1);
    }
    __syncthreads();
    for (int t = tid; t < nb; t += 512) {
        int c = lh[t];
        lb[t] = c ? atomicAdd(&cur[t], c) : 0;
        lh[t] = 0;
    }
    __syncthreads();
    if (isKg) {
#pragma unroll
        for (int j = 0; j < EPT; ++j) {
            int h = hreg[j];
            if (h >= 0) {
                int i = base + j * 512 + tid;
                int b = h >> RSHIFT;
                int p = lb[b] + atomicAdd(&lh[b], 1);
                kgPay[p] = tail[i] | ((etype[i] - 1) << 17) | ((h & (BROWS - 1)) << 21);
            }
        }
    } else {
#pragma unroll
        for (int j = 0; j < EPT; ++j) {
            int h = hreg[j];
            if (h >= 0) {
                int i = base + j * 512 + tid;
                int b = h >> RSHIFT;
                int p = lb[b] + atomicAdd(&lh[b], 1);
                uPay[p] = make_int2(ucols[i] | ((h & (BROWS - 1)) << 17),
                                    __float_as_int(uvals[i]));
            }
        }
    }
}

// ============================================================================
// Pass 3 (merged): accumulate directly into a 128x64 f32 LDS tile with LDS
// float atomics (ds_add_f32) -- no counting sort, single payload read, no
// barriers in the main loop.  2 edges per wave per iteration (float2/lane,
// half-wave per edge); the two ds_add instructions are parity-staggered so
// each touches all 32 banks exactly 2-way (free).
// blocks [0,NBU): user buckets (longer: 2x edges + attention epilogue --
// dispatched FIRST so the dispatch tail is short kg blocks);
// blocks [NBU, NBU+NBK): kg buckets (mean fused).
// ============================================================================
__global__ __launch_bounds__(1024, 8) void acc_both(
        const int* __restrict__ kgPay, const int* __restrict__ kgOffs,
        const int2* __restrict__ uPay, const int* __restrict__ uOffs,
        const float* __restrict__ entity_emb,
        const float* __restrict__ weight,
        const float* __restrict__ user_emb,
        const float* __restrict__ P,
        const float* __restrict__ cvec,
        const float* __restrict__ W_user_att,
        const float* __restrict__ b_user_att,
        const float* __restrict__ latent_new,
        float* __restrict__ ent_out,
        float* __restrict__ user_out) {
    __shared__ float accum[BROWS * EMB];     // 32 KB
    __shared__ int   lcnt[BROWS];
    int t  = threadIdx.x;
    int wv = t >> 6, l = t & 63;             // wv 0..15
    int h  = l >> 5, dd = l & 31;            // pair half / intra-row float2 idx
    int lane2 = (wv << 1) + h;               // edge slot 0..31 within iteration

    float4* a4 = (float4*)accum;
    a4[t]        = make_float4(0.f, 0.f, 0.f, 0.f);
    a4[t + 1024] = make_float4(0.f, 0.f, 0.f, 0.f);
    if (t < BROWS) lcnt[t] = 0;
    __syncthreads();

    const float2* e2 = (const float2*)entity_emb;

    if (blockIdx.x < NBU) {
        // ---------------- USER bucket ----------------
        int bk = blockIdx.x;
        int start = uOffs[bk], n = uOffs[bk + 1] - start;
        const int2* pay = uPay + start;
        int nIt = (n + 31) >> 5;
#pragma unroll 2
        for (int it = 0; it < nIt; ++it) {
            int ie = (it << 5) + lane2;
            if (ie < n) {
                int2 v = pay[ie];
                int col = v.x & 0x1FFFF;
                int r   = (v.x >> 17) & (BROWS - 1);
                float val = __int_as_float(v.y);
                float2 e = e2[(col << 5) + dd];
                float p0 = val * e.x, p1 = val * e.y;
                int wb = (r << 6) + (dd << 1);
                atomicAdd(&accum[wb + h],       h ? p1 : p0);
                atomicAdd(&accum[wb + (1 ^ h)], h ? p0 : p1);
            }
        }
        __syncthreads();

        int rowbase = bk * BROWS;
        for (int k = 0; k < BROWS / 16; ++k) {
            int r = (k << 4) + wv;
            int gr = rowbase + r;
            if (gr >= N_USERS) break;            // wave-uniform; last bucket only
            float acc = accum[(r << 6) + l];

            // fused attention gating epilogue for this row
            float ue = user_emb[(size_t)gr * EMB + l];
            float s[8];
#pragma unroll
            for (int f = 0; f < 8; ++f) s[f] = ue * P[l * 8 + f];
#pragma unroll
            for (int off = 32; off; off >>= 1) {
#pragma unroll
                for (int f = 0; f < 8; ++f) s[f] += __shfl_xor(s[f], off, 64);
            }
#pragma unroll
            for (int f = 0; f < 8; ++f) s[f] += cvec[f];
            float att[8];
            float mx = -1e30f;
#pragma unroll
            for (int q = 0; q < 8; ++q) {
                float a = b_user_att[q];
#pragma unroll
                for (int j = 0; j < 8; ++j) a += s[j] * W_user_att[q * 8 + j];
                a = a > 0.f ? a : SLOPE * a;
                att[q] = a;
                mx = fmaxf(mx, a);
            }
            float sum = 0.f;
#pragma unroll
            for (int q = 0; q < 8; ++q) { att[q] = __expf(att[q] - mx); sum += att[q]; }
            float inv = 1.f / sum;
            float g = 0.f;
#pragma unroll
            for (int f = 0; f < 8; ++f) g += att[f] * inv * latent_new[f * EMB + l];
            user_out[(size_t)gr * EMB + l] = acc * (1.f + g);
        }
    } else {
        // ---------------- KG bucket ----------------
        int bk = blockIdx.x - NBU;
        int start = kgOffs[bk], n = kgOffs[bk + 1] - start;
        const int* pay = kgPay + start;
        int nIt = (n + 31) >> 5;
#pragma unroll 2
        for (int it = 0; it < nIt; ++it) {
            int ie = (it << 5) + lane2;
            if (ie < n) {
                int v  = pay[ie];
                int tl = v & 0x1FFFF;
                int w  = (v >> 17) & 15;
                int r  = (v >> 21) & (BROWS - 1);
                float2 e  = e2[(tl << 5) + dd];
                float2 wt = *((const float2*)weight + ((w << 5) + dd));
                float p0 = e.x * wt.x, p1 = e.y * wt.y;
                int wb = (r << 6) + (dd << 1);
                atomicAdd(&accum[wb + h],       h ? p1 : p0);
                atomicAdd(&accum[wb + (1 ^ h)], h ? p0 : p1);
                if (dd == 0) atomicAdd(&lcnt[r], 1);
            }
        }
        __syncthreads();

        int rowbase = bk * BROWS;
#pragma unroll
        for (int k = 0; k < BROWS / 16; ++k) {
            int r = (k << 4) + wv;
            int gr = rowbase + r;
            if (gr < N_ENTITIES)
                ent_out[(size_t)gr * EMB + l] =
                    accum[(r << 6) + l] / fmaxf((float)lcnt[r], 1.f);
        }
    }
}

// ============================================================================
// Fallback atomic path (verified) — only if ws too small
// ============================================================================
__global__ void kg_scatter(const int* __restrict__ head, const int* __restrict__ tail,
                           const int* __restrict__ etype,
                           const float* __restrict__ entity_emb,
                           const float* __restrict__ weight,
                           float* __restrict__ sums, float* __restrict__ cnt) {
    int gid = blockIdx.x * blockDim.x + threadIdx.x;
    int e = gid >> 6, d = threadIdx.x & 63;
    if (e >= N_EDGES) return;
    int h = head[e], t = tail[e], w = etype[e] - 1;
    float v = entity_emb[t * EMB + d] * weight[w * EMB + d];
    unsafeAtomicAdd(&sums[h * EMB + d], v);
    if (d == 0) unsafeAtomicAdd(&cnt[h], 1.0f);
}

__global__ void user_scatter(const int* __restrict__ rows, const int* __restrict__ cols,
                             const float* __restrict__ vals,
                             const float* __restrict__ entity_emb,
                             float* __restrict__ user_sums) {
    int gid = blockIdx.x * blockDim.x + threadIdx.x;
    int e = gid >> 6, d = threadIdx.x & 63;
    if (e >= NNZ) return;
    float v = vals[e] * entity_emb[cols[e] * EMB + d];
    unsafeAtomicAdd(&user_sums[rows[e] * EMB + d], v);
}

__global__ void entity_div(float* __restrict__ ent, const float* __restrict__ cnt) {
    int gid = blockIdx.x * blockDim.x + threadIdx.x;
    if (gid >= N_ENTITIES * EMB) return;
    float c = cnt[gid >> 6];
    ent[gid] = ent[gid] / fmaxf(c, 1.0f);
}

__global__ void user_finalize(const float* __restrict__ user_emb,
                              const float* __restrict__ P,
                              const float* __restrict__ c,
                              const float* __restrict__ W_user_att,
                              const float* __restrict__ b_user_att,
                              const float* __restrict__ latent_new,
                              float* __restrict__ user_out) {
    int gid = blockIdx.x * blockDim.x + threadIdx.x;
    int u = gid >> 6, lane = threadIdx.x & 63;
    if (u >= N_USERS) return;
    float ue = user_emb[u * 64 + lane];
    float s[8];
#pragma unroll
    for (int f = 0; f < 8; ++f) s[f] = ue * P[lane * 8 + f];
#pragma unroll
    for (int off = 32; off; off >>= 1)
#pragma unroll
        for (int f = 0; f < 8; ++f) s[f] += __shfl_xor(s[f], off, 64);
#pragma unroll
    for (int f = 0; f < 8; ++f) s[f] += c[f];
    float att[8], mx = -1e30f;
#pragma unroll
    for (int k = 0; k < 8; ++k) {
        float a = b_user_att[k];
#pragma unroll
        for (int j = 0; j < 8; ++j) a += s[j] * W_user_att[k * 8 + j];
        a = a > 0.f ? a : SLOPE * a;
        att[k] = a;
        mx = fmaxf(mx, a);
    }
    float sum = 0.f;
#pragma unroll
    for (int k = 0; k < 8; ++k) { att[k] = expf(att[k] - mx); sum += att[k]; }
    float inv = 1.f / sum, g = 0.f;
#pragma unroll
    for (int f = 0; f < 8; ++f) g += att[f] * inv * latent_new[f * 64 + lane];
    float ua = user_out[u * 64 + lane];
    user_out[u * 64 + lane] = ua * (1.f + g);
}

extern "C" void kernel_launch(void* const* d_in, const int* in_sizes, int n_in,
                              void* d_out, int out_size, void* d_ws, size_t ws_size,
                              hipStream_t stream) {
    const float* entity_emb   = (const float*)d_in[0];
    const float* user_emb     = (const float*)d_in[1];
    const float* latent_emb   = (const float*)d_in[2];
    const int*   edge_index   = (const int*)d_in[3];
    const int*   edge_type    = (const int*)d_in[4];
    const int*   irows        = (const int*)d_in[5];
    const int*   icols        = (const int*)d_in[6];
    const float* ivals        = (const float*)d_in[7];
    const float* weight       = (const float*)d_in[8];
    const float* W_user_att   = (const float*)d_in[10];
    const float* b_user_att   = (const float*)d_in[11];
    const float* W_weight_att = (const float*)d_in[12];
    const float* b_weight_att = (const float*)d_in[13];
    const float* W1           = (const float*)d_in[14];
    const float* b1           = (const float*)d_in[15];
    const float* W2           = (const float*)d_in[16];
    const float* b2           = (const float*)d_in[17];

    float* out      = (float*)d_out;
    float* ent_out  = out;
    float* user_out = out + (size_t)N_ENTITIES * EMB;
    float* lat_out  = user_out + (size_t)N_USERS * EMB;

    const int* head = edge_index;
    const int* tail = edge_index + N_EDGES;

    // ---- workspace layout ----
    int* ws_i = (int*)d_ws;
    int*   kgOffs = ws_i;                       // NBK+1 = 783
    int*   uOffs  = kgOffs + (NBK + 1);         // NBU+1 = 392
    int*   kgCur  = uOffs + (NBU + 1);          // 782
    int*   uCur   = kgCur + NBK;                // 391
    int*   kgPay  = uCur + NBU;                 // 2,000,000 int
    int2*  uPay   = (int2*)(kgPay + N_EDGES);   // 2,000,000 int2 (8 B aligned)
    float* Pbuf   = (float*)(uPay + NNZ);       // 512
    float* cbuf   = Pbuf + 64 * 8;              // 8
    size_t need_bytes = (size_t)((NBK + 1) + (NBU + 1) + NBK + NBU +
                                 N_EDGES + 2 * (size_t)NNZ + 512 + 8) * 4;

    if (ws_size >= need_bytes) {
        // zero both histogram regions in one memset (contiguous)
        hipMemsetAsync(kgOffs, 0, (size_t)((NBK + 1) + (NBU + 1)) * sizeof(int), stream);

        hist_both<<<PB, 512, 0, stream>>>(head, irows, kgOffs, uOffs);
        scan_both<<<2, 1024, 0, stream>>>(kgOffs, kgCur, uOffs, uCur);
        scatter_both<<<2 * PB + 1, 512, 0, stream>>>(head, tail, edge_type, kgCur, kgPay,
                                                     irows, icols, ivals, uCur, uPay,
                                                     latent_emb, weight, W_weight_att,
                                                     b_weight_att, W1, b1, W2, b2,
                                                     Pbuf, cbuf, lat_out);
        acc_both<<<NBK + NBU, 1024, 0, stream>>>(kgPay, kgOffs, uPay, uOffs,
                                                 entity_emb, weight, user_emb,
                                                 Pbuf, cbuf, W_user_att, b_user_att,
                                                 lat_out, ent_out, user_out);
    } else {
        // ---------- fallback atomic path ----------
        float* cnt   = (float*)d_ws;
        float* Pbuf2 = cnt + N_ENTITIES;
        float* cbuf2 = Pbuf2 + 64 * 8;
        hipMemsetAsync(ent_out, 0,
                       (size_t)(N_ENTITIES + N_USERS) * EMB * sizeof(float), stream);
        hipMemsetAsync(cnt, 0, N_ENTITIES * sizeof(float), stream);
        int blocks_edges = (N_EDGES * 64) / 256;
        kg_scatter<<<blocks_edges, 256, 0, stream>>>(head, tail, edge_type, entity_emb,
                                                     weight, ent_out, cnt);
        user_scatter<<<blocks_edges, 256, 0, stream>>>(irows, icols, ivals, entity_emb,
                                                       user_out);
        small_dense<<<1, 64, 0, stream>>>(latent_emb, weight, W_weight_att,
                                          b_weight_att, W1, b1, W2, b2,
                                          Pbuf2, cbuf2, lat_out);
        user_finalize<<<(N_USERS * 64) / 256, 256, 0, stream>>>(user_emb, Pbuf2, cbuf2,
                                                                W_user_att, b_user_att,
                                                                lat_out, user_out);
        entity_div<<<(N_ENTITIES * EMB) / 256, 256, 0, stream>>>(ent_out, cnt);
    }
}

// Round 2
// 397.658 us; speedup vs baseline: 4.3708x; 4.3708x over previous
//
#include <hip/hip_runtime.h>

#define N_USERS    50000
#define N_ENTITIES 100000
#define EMB        64
#define N_EDGES    2000000
#define NNZ        2000000
#define SLOPE      0.2f

// ---- bucket geometry (round-0 verified) ------------------------------------
#define KROWS   256                 // entity rows per kg bucket
#define KSHIFT  8
#define NBK     391                 // ceil(100000/256)
#define UROWS   128                 // user rows per bucket
#define USHIFT  7
#define NBU     391                 // ceil(50000/128)
#define CAPK    8192                // LDS payload capacity (kg, 4 B)
#define CAPU    7680                // LDS payload capacity (user, 8 B)
#define CHUNK   8192                // edges per partition block
#define EPT     (CHUNK / 512)       // 16 keys staged per thread
#define PB      ((N_EDGES + CHUNK - 1) / CHUNK)      // 245
#define NQ      (NBK + NBU)         // 782 buckets in steal queue
#define ACCBLK  512                 // persistent acc blocks (2/CU thread-cap)

// ============================================================================
// Pass 0: fused bucket histograms (LDS-privatized)
// ============================================================================
__global__ __launch_bounds__(512) void hist_both(const int* __restrict__ head,
                                                 const int* __restrict__ urows,
                                                 int* __restrict__ kgOffs,
                                                 int* __restrict__ uOffs) {
    __shared__ int lhk[NBK];
    __shared__ int lhu[NBU];
    int tid = threadIdx.x;
    for (int t = tid; t < NBK; t += 512) lhk[t] = 0;
    for (int t = tid; t < NBU; t += 512) lhu[t] = 0;
    __syncthreads();
    int base = blockIdx.x * CHUNK;
#pragma unroll 4
    for (int j = 0; j < EPT; ++j) {
        int i = base + j * 512 + tid;
        if (i < N_EDGES) atomicAdd(&lhk[head[i] >> KSHIFT], 1);
        if (i < NNZ)     atomicAdd(&lhu[urows[i] >> USHIFT], 1);
    }
    __syncthreads();
    for (int t = tid; t < NBK; t += 512) { int c = lhk[t]; if (c) atomicAdd(&kgOffs[t], c); }
    for (int t = tid; t < NBU; t += 512) { int c = lhu[t]; if (c) atomicAdd(&uOffs[t], c); }
}

// ============================================================================
// Pass 1: exclusive scan of both bucket histograms (grid = 2 blocks)
// ============================================================================
__global__ __launch_bounds__(512) void scan_both(int* __restrict__ kgOffs,
                                                 int* __restrict__ kgCur,
                                                 int* __restrict__ uOffs,
                                                 int* __restrict__ uCur) {
    __shared__ int tsum[512];
    int n     = (blockIdx.x == 0) ? NBK : NBU;   // both 391
    int* offs = (blockIdx.x == 0) ? kgOffs : uOffs;
    int* cur  = (blockIdx.x == 0) ? kgCur  : uCur;
    int tid = threadIdx.x;
    int v = (tid < n) ? offs[tid] : 0;
    tsum[tid] = v;
    __syncthreads();
    for (int off = 1; off < 512; off <<= 1) {
        int t = (tid >= off) ? tsum[tid - off] : 0;
        __syncthreads();
        tsum[tid] += t;
        __syncthreads();
    }
    if (tid < n) { int e = tsum[tid] - v; offs[tid] = e; cur[tid] = e; }
    if (tid == n - 1) offs[n] = tsum[tid];
}

// ============================================================================
// Small dense math: latent_new, P = W1^T*lat1^T, c = b1*lat1^T.
// Device function so it can be fused into scatter_both (extra block).
// All threads of the calling block must enter (barriers by everyone).
// ============================================================================
__device__ void small_dense_body(int l,
                                 const float* __restrict__ latent_emb,
                                 const float* __restrict__ weight,
                                 const float* __restrict__ W_weight_att,
                                 const float* __restrict__ b_weight_att,
                                 const float* __restrict__ W1,
                                 const float* __restrict__ b1,
                                 const float* __restrict__ W2,
                                 const float* __restrict__ b2,
                                 float* __restrict__ P_out,
                                 float* __restrict__ c_out,
                                 float* __restrict__ latent_new_out) {
    __shared__ float lat1[8 * 64];
    __shared__ float lat2[8 * 64];
    __shared__ float wl2[16 * 64];
    __shared__ float srp[8 * 16];
    __shared__ float soft[8 * 16];

    if (l < 64) {
        for (int f = 0; f < 8; ++f) {
            float a1 = b1[l], a2 = b2[l];
            for (int k = 0; k < 64; ++k) {
                float le = latent_emb[f * 64 + k];
                a1 += le * W1[l * 64 + k];
                a2 += le * W2[l * 64 + k];
            }
            lat1[f * 64 + l] = a1;
            lat2[f * 64 + l] = a2;
        }
        for (int r = 0; r < 16; ++r) {
            float a = b2[l];
            for (int k = 0; k < 64; ++k) a += weight[r * 64 + k] * W2[l * 64 + k];
            wl2[r * 64 + l] = a;
        }
    }
    __syncthreads();

    if (l < 64) {
        for (int f = 0; f < 8; ++f) {
            float p = 0.f;
            for (int d = 0; d < 64; ++d) p += W1[d * 64 + l] * lat1[f * 64 + d];
            P_out[l * 8 + f] = p;
        }
        if (l < 8) {
            float cc = 0.f;
            for (int d = 0; d < 64; ++d) cc += b1[d] * lat1[l * 64 + d];
            c_out[l] = cc;
        }
        for (int idx = l; idx < 128; idx += 64) {
            int f = idx >> 4, r = idx & 15;
            float a = 0.f;
            for (int d = 0; d < 64; ++d) a += lat2[f * 64 + d] * wl2[r * 64 + d];
            srp[idx] = a;
        }
    }
    __syncthreads();

    if (l < 8) {
        int f = l;
        float att[16];
        float mx = -1e30f;
        for (int k = 0; k < 16; ++k) {
            float a = b_weight_att[k];
            for (int j = 0; j < 16; ++j) a += srp[f * 16 + j] * W_weight_att[k * 16 + j];
            a = a > 0.f ? a : SLOPE * a;
            att[k] = a;
            mx = fmaxf(mx, a);
        }
        float s = 0.f;
        for (int k = 0; k < 16; ++k) { att[k] = expf(att[k] - mx); s += att[k]; }
        float inv = 1.f / s;
        for (int k = 0; k < 16; ++k) soft[f * 16 + k] = att[k] * inv;
    }
    __syncthreads();

    if (l < 64) {
        for (int f = 0; f < 8; ++f) {
            float a = 0.f;
            for (int r = 0; r < 16; ++r) a += soft[f * 16 + r] * weight[r * 64 + l];
            latent_new_out[f * 64 + l] = a;
        }
    }
}

__global__ void small_dense(const float* __restrict__ latent_emb,
                            const float* __restrict__ weight,
                            const float* __restrict__ W_weight_att,
                            const float* __restrict__ b_weight_att,
                            const float* __restrict__ W1,
                            const float* __restrict__ b1,
                            const float* __restrict__ W2,
                            const float* __restrict__ b2,
                            float* __restrict__ P_out,
                            float* __restrict__ c_out,
                            float* __restrict__ latent_new_out) {
    small_dense_body(threadIdx.x, latent_emb, weight, W_weight_att, b_weight_att,
                     W1, b1, W2, b2, P_out, c_out, latent_new_out);
}

// ============================================================================
// Pass 2 (merged): bucket partition with block-local reservation.
// blocks [0,PB) = kg edges; [PB,2*PB) = user nnz; block 2*PB = small dense.
// Keys are register-staged (single global read of head/urows).
// kg payload: tail(0..16) | type-1 (17..20) | rowlow (21..28)
// user payload: int2 { col(0..16) | rowlow(17..23), val_bits }
// ============================================================================
__global__ __launch_bounds__(512) void scatter_both(const int* __restrict__ head,
                                                    const int* __restrict__ tail,
                                                    const int* __restrict__ etype,
                                                    int* __restrict__ kgCur,
                                                    int* __restrict__ kgPay,
                                                    const int* __restrict__ urows,
                                                    const int* __restrict__ ucols,
                                                    const float* __restrict__ uvals,
                                                    int* __restrict__ uCur,
                                                    int2* __restrict__ uPay,
                                                    const float* __restrict__ latent_emb,
                                                    const float* __restrict__ weight,
                                                    const float* __restrict__ W_weight_att,
                                                    const float* __restrict__ b_weight_att,
                                                    const float* __restrict__ W1,
                                                    const float* __restrict__ b1,
                                                    const float* __restrict__ W2,
                                                    const float* __restrict__ b2,
                                                    float* __restrict__ Pbuf,
                                                    float* __restrict__ cbuf,
                                                    float* __restrict__ lat_out) {
    if (blockIdx.x == 2 * PB) {
        small_dense_body(threadIdx.x, latent_emb, weight, W_weight_att,
                         b_weight_att, W1, b1, W2, b2, Pbuf, cbuf, lat_out);
        return;
    }

    __shared__ int lh[NBK];      // NBK == NBU == 391
    __shared__ int lb[NBK];
    int tid = threadIdx.x;
    bool isKg = blockIdx.x < PB;
    int base = (isKg ? blockIdx.x : blockIdx.x - PB) * CHUNK;
    int nTot = isKg ? N_EDGES : NNZ;
    int shift = isKg ? KSHIFT : USHIFT;
    const int* src = isKg ? head : urows;
    int* cur = isKg ? kgCur : uCur;

    for (int t = tid; t < NBK; t += 512) lh[t] = 0;
    __syncthreads();

    int hreg[EPT];                       // register-staged keys (read once)
#pragma unroll
    for (int j = 0; j < EPT; ++j) {
        int i = base + j * 512 + tid;
        int h = (i < nTot) ? src[i] : -1;
        hreg[j] = h;
        if (h >= 0) atomicAdd(&lh[h >> shift], 1);
    }
    __syncthreads();
    for (int t = tid; t < NBK; t += 512) {
        int c = lh[t];
        lb[t] = c ? atomicAdd(&cur[t], c) : 0;
        lh[t] = 0;
    }
    __syncthreads();
    if (isKg) {
#pragma unroll
        for (int j = 0; j < EPT; ++j) {
            int h = hreg[j];
            if (h >= 0) {
                int i = base + j * 512 + tid;
                int b = h >> KSHIFT;
                int p = lb[b] + atomicAdd(&lh[b], 1);
                kgPay[p] = tail[i] | ((etype[i] - 1) << 17) | ((h & (KROWS - 1)) << 21);
            }
        }
    } else {
#pragma unroll
        for (int j = 0; j < EPT; ++j) {
            int h = hreg[j];
            if (h >= 0) {
                int i = base + j * 512 + tid;
                int b = h >> USHIFT;
                int p = lb[b] + atomicAdd(&lh[b], 1);
                uPay[p] = make_int2(ucols[i] | ((h & (UROWS - 1)) << 17),
                                    __float_as_int(uvals[i]));
            }
        }
    }
}

// ============================================================================
// Pass 3: persistent work-stealing accumulate (round-0 verified bucket body).
// Grid = 512 resident blocks; buckets pulled from a global atomic queue
// (user buckets first, then kg) — removes the 782-block dispatch tail.
// Per bucket: in-LDS counting sort to exact row, per-wave register
// accumulation, mean / attention-gating fused.
// ============================================================================
__global__ __launch_bounds__(1024, 8) void acc_both(
        const int* __restrict__ kgPay, const int* __restrict__ kgOffs,
        const int2* __restrict__ uPay, const int* __restrict__ uOffs,
        const float* __restrict__ entity_emb,
        const float* __restrict__ weight,
        const float* __restrict__ user_emb,
        const float* __restrict__ P,
        const float* __restrict__ cvec,
        const float* __restrict__ W_user_att,
        const float* __restrict__ b_user_att,
        const float* __restrict__ latent_new,
        int* __restrict__ qCtr,
        float* __restrict__ ent_out,
        float* __restrict__ user_out) {
    __shared__ long long smem8[7873];   // 62984 B union
    __shared__ int sbk;
    int t = threadIdx.x, d = t & 63, wv = t >> 6;    // wv 0..15

    for (;;) {
        __syncthreads();                 // previous bucket's LDS reads done
        if (t == 0) sbk = atomicAdd(qCtr, 1);
        __syncthreads();
        int q = sbk;
        if (q >= NQ) return;             // uniform exit

        if (q < NBU) {
            // ---------------- USER bucket ----------------
            int2* spay = (int2*)smem8;               // CAPU int2
            int* lcnt = (int*)(spay + CAPU);         // 128
            int* lofs = lcnt + UROWS;                // 129
            int* sc   = lofs + UROWS + 1;            // 128
            int bk = q;
            int start = uOffs[bk], end = uOffs[bk + 1];
            int n = end - start; if (n > CAPU) n = CAPU;

            if (t < UROWS) lcnt[t] = 0;
            __syncthreads();
            for (int i = t; i < n; i += 1024)
                atomicAdd(&lcnt[(uPay[start + i].x >> 17) & (UROWS - 1)], 1);
            __syncthreads();
            if (t < UROWS) sc[t] = lcnt[t];
            __syncthreads();
            for (int off = 1; off < UROWS; off <<= 1) {
                int v = (t < UROWS && t >= off) ? sc[t - off] : 0;
                __syncthreads();
                if (t < UROWS) sc[t] += v;
                __syncthreads();
            }
            if (t < UROWS) { int e = sc[t] - lcnt[t]; lofs[t] = e; lcnt[t] = e; }
            if (t == 0) lofs[UROWS] = n;
            __syncthreads();
            for (int i = t; i < n; i += 1024) {
                int2 v = uPay[start + i];
                int p = atomicAdd(&lcnt[(v.x >> 17) & (UROWS - 1)], 1);
                spay[p] = v;
            }
            __syncthreads();

            int rowbase = bk * UROWS;
            for (int rr = 0; rr < UROWS / 16; ++rr) {
                int r = wv * (UROWS / 16) + rr;
                int gr = rowbase + r;
                if (gr >= N_USERS) break;             // wave-uniform; last bucket only
                int s0 = lofs[r], e0 = lofs[r + 1];
                float acc = 0.f;
                int i = s0;
                for (; i + 7 < e0; i += 8) {
                    float a0 = 0.f, a1 = 0.f;
#pragma unroll
                    for (int u = 0; u < 8; u += 2) {
                        int2 va = spay[i + u], vb = spay[i + u + 1];
                        a0 += __int_as_float(va.y) * entity_emb[(va.x & 0x1FFFF) * EMB + d];
                        a1 += __int_as_float(vb.y) * entity_emb[(vb.x & 0x1FFFF) * EMB + d];
                    }
                    acc += a0 + a1;
                }
                for (; i < e0; ++i) {
                    int2 v = spay[i];
                    acc += __int_as_float(v.y) * entity_emb[(v.x & 0x1FFFF) * EMB + d];
                }
                for (int j = start + CAPU; j < end; ++j) {   // overflow (never taken)
                    int2 v = uPay[j];
                    if (((v.x >> 17) & (UROWS - 1)) == r)
                        acc += __int_as_float(v.y) * entity_emb[(v.x & 0x1FFFF) * EMB + d];
                }

                // fused attention gating epilogue for this row
                float ue = user_emb[gr * EMB + d];
                float s[8];
#pragma unroll
                for (int f = 0; f < 8; ++f) s[f] = ue * P[d * 8 + f];
#pragma unroll
                for (int off = 32; off; off >>= 1) {
#pragma unroll
                    for (int f = 0; f < 8; ++f) s[f] += __shfl_xor(s[f], off, 64);
                }
#pragma unroll
                for (int f = 0; f < 8; ++f) s[f] += cvec[f];
                float att[8];
                float mx = -1e30f;
#pragma unroll
                for (int k = 0; k < 8; ++k) {
                    float a = b_user_att[k];
#pragma unroll
                    for (int j = 0; j < 8; ++j) a += s[j] * W_user_att[k * 8 + j];
                    a = a > 0.f ? a : SLOPE * a;
                    att[k] = a;
                    mx = fmaxf(mx, a);
                }
                float sum = 0.f;
#pragma unroll
                for (int k = 0; k < 8; ++k) { att[k] = __expf(att[k] - mx); sum += att[k]; }
                float inv = 1.f / sum;
                float g = 0.f;
#pragma unroll
                for (int f = 0; f < 8; ++f) g += att[f] * inv * latent_new[f * EMB + d];
                user_out[gr * EMB + d] = acc * (1.f + g);
            }
        } else {
            // ---------------- KG bucket ----------------
            int* spay = (int*)smem8;                 // CAPK ints
            int* lcnt = spay + CAPK;                 // 256
            int* lofs = lcnt + KROWS;                // 257
            int* sc   = lofs + KROWS + 1;            // 256
            int bk = q - NBU;
            int start = kgOffs[bk], end = kgOffs[bk + 1];
            int n = end - start; if (n > CAPK) n = CAPK;

            if (t < KROWS) lcnt[t] = 0;
            __syncthreads();
            for (int i = t; i < n; i += 1024)
                atomicAdd(&lcnt[(kgPay[start + i] >> 21) & (KROWS - 1)], 1);
            __syncthreads();
            if (t < KROWS) sc[t] = lcnt[t];
            __syncthreads();
            for (int off = 1; off < KROWS; off <<= 1) {
                int v = (t < KROWS && t >= off) ? sc[t - off] : 0;
                __syncthreads();
                if (t < KROWS) sc[t] += v;
                __syncthreads();
            }
            if (t < KROWS) { int e = sc[t] - lcnt[t]; lofs[t] = e; lcnt[t] = e; }
            if (t == 0) lofs[KROWS] = n;
            __syncthreads();
            for (int i = t; i < n; i += 1024) {
                int v = kgPay[start + i];
                int p = atomicAdd(&lcnt[(v >> 21) & (KROWS - 1)], 1);
                spay[p] = v;
            }
            __syncthreads();

            int rowbase = bk * KROWS;
            for (int rr = 0; rr < KROWS / 16; ++rr) {
                int r = wv * (KROWS / 16) + rr;
                int gr = rowbase + r;
                if (gr >= N_ENTITIES) break;          // wave-uniform; last bucket only
                int s0 = lofs[r], e0 = lofs[r + 1];
                int cnt = e0 - s0;
                float acc = 0.f;
                int i = s0;
                for (; i + 7 < e0; i += 8) {
                    float a0 = 0.f, a1 = 0.f;
#pragma unroll
                    for (int u = 0; u < 8; u += 2) {
                        int va = spay[i + u], vb = spay[i + u + 1];
                        a0 += entity_emb[(va & 0x1FFFF) * EMB + d] * weight[((va >> 17) & 15) * EMB + d];
                        a1 += entity_emb[(vb & 0x1FFFF) * EMB + d] * weight[((vb >> 17) & 15) * EMB + d];
                    }
                    acc += a0 + a1;
                }
                for (; i < e0; ++i) {
                    int v = spay[i];
                    acc += entity_emb[(v & 0x1FFFF) * EMB + d] * weight[((v >> 17) & 15) * EMB + d];
                }
                // overflow tail (statistically never taken)
                for (int j = start + CAPK; j < end; ++j) {
                    int v = kgPay[j];
                    if (((v >> 21) & (KROWS - 1)) == r) {
                        acc += entity_emb[(v & 0x1FFFF) * EMB + d] * weight[((v >> 17) & 15) * EMB + d];
                        ++cnt;
                    }
                }
                ent_out[gr * EMB + d] = acc / fmaxf((float)cnt, 1.f);
            }
        }
    }
}

// ============================================================================
// Fallback atomic path (verified) — only if ws too small
// ============================================================================
__global__ void kg_scatter(const int* __restrict__ head, const int* __restrict__ tail,
                           const int* __restrict__ etype,
                           const float* __restrict__ entity_emb,
                           const float* __restrict__ weight,
                           float* __restrict__ sums, float* __restrict__ cnt) {
    int gid = blockIdx.x * blockDim.x + threadIdx.x;
    int e = gid >> 6, d = threadIdx.x & 63;
    if (e >= N_EDGES) return;
    int h = head[e], t = tail[e], w = etype[e] - 1;
    float v = entity_emb[t * EMB + d] * weight[w * EMB + d];
    unsafeAtomicAdd(&sums[h * EMB + d], v);
    if (d == 0) unsafeAtomicAdd(&cnt[h], 1.0f);
}

__global__ void user_scatter(const int* __restrict__ rows, const int* __restrict__ cols,
                             const float* __restrict__ vals,
                             const float* __restrict__ entity_emb,
                             float* __restrict__ user_sums) {
    int gid = blockIdx.x * blockDim.x + threadIdx.x;
    int e = gid >> 6, d = threadIdx.x & 63;
    if (e >= NNZ) return;
    float v = vals[e] * entity_emb[cols[e] * EMB + d];
    unsafeAtomicAdd(&user_sums[rows[e] * EMB + d], v);
}

__global__ void entity_div(float* __restrict__ ent, const float* __restrict__ cnt) {
    int gid = blockIdx.x * blockDim.x + threadIdx.x;
    if (gid >= N_ENTITIES * EMB) return;
    float c = cnt[gid >> 6];
    ent[gid] = ent[gid] / fmaxf(c, 1.0f);
}

__global__ void user_finalize(const float* __restrict__ user_emb,
                              const float* __restrict__ P,
                              const float* __restrict__ c,
                              const float* __restrict__ W_user_att,
                              const float* __restrict__ b_user_att,
                              const float* __restrict__ latent_new,
                              float* __restrict__ user_out) {
    int gid = blockIdx.x * blockDim.x + threadIdx.x;
    int u = gid >> 6, lane = threadIdx.x & 63;
    if (u >= N_USERS) return;
    float ue = user_emb[u * 64 + lane];
    float s[8];
#pragma unroll
    for (int f = 0; f < 8; ++f) s[f] = ue * P[lane * 8 + f];
#pragma unroll
    for (int off = 32; off; off >>= 1)
#pragma unroll
        for (int f = 0; f < 8; ++f) s[f] += __shfl_xor(s[f], off, 64);
#pragma unroll
    for (int f = 0; f < 8; ++f) s[f] += c[f];
    float att[8], mx = -1e30f;
#pragma unroll
    for (int k = 0; k < 8; ++k) {
        float a = b_user_att[k];
#pragma unroll
        for (int j = 0; j < 8; ++j) a += s[j] * W_user_att[k * 8 + j];
        a = a > 0.f ? a : SLOPE * a;
        att[k] = a;
        mx = fmaxf(mx, a);
    }
    float sum = 0.f;
#pragma unroll
    for (int k = 0; k < 8; ++k) { att[k] = expf(att[k] - mx); sum += att[k]; }
    float inv = 1.f / sum, g = 0.f;
#pragma unroll
    for (int f = 0; f < 8; ++f) g += att[f] * inv * latent_new[f * 64 + lane];
    float ua = user_out[u * 64 + lane];
    user_out[u * 64 + lane] = ua * (1.f + g);
}

extern "C" void kernel_launch(void* const* d_in, const int* in_sizes, int n_in,
                              void* d_out, int out_size, void* d_ws, size_t ws_size,
                              hipStream_t stream) {
    const float* entity_emb   = (const float*)d_in[0];
    const float* user_emb     = (const float*)d_in[1];
    const float* latent_emb   = (const float*)d_in[2];
    const int*   edge_index   = (const int*)d_in[3];
    const int*   edge_type    = (const int*)d_in[4];
    const int*   irows        = (const int*)d_in[5];
    const int*   icols        = (const int*)d_in[6];
    const float* ivals        = (const float*)d_in[7];
    const float* weight       = (const float*)d_in[8];
    const float* W_user_att   = (const float*)d_in[10];
    const float* b_user_att   = (const float*)d_in[11];
    const float* W_weight_att = (const float*)d_in[12];
    const float* b_weight_att = (const float*)d_in[13];
    const float* W1           = (const float*)d_in[14];
    const float* b1           = (const float*)d_in[15];
    const float* W2           = (const float*)d_in[16];
    const float* b2           = (const float*)d_in[17];

    float* out      = (float*)d_out;
    float* ent_out  = out;
    float* user_out = out + (size_t)N_ENTITIES * EMB;
    float* lat_out  = user_out + (size_t)N_USERS * EMB;

    const int* head = edge_index;
    const int* tail = edge_index + N_EDGES;

    // ---- workspace layout ----
    int* ws_i = (int*)d_ws;
    int*   kgOffs = ws_i;                       // NBK+1 = 392
    int*   uOffs  = kgOffs + (NBK + 1);         // NBU+1 = 392
    int*   qCtr   = uOffs + (NBU + 1);          // 2 (pad keeps uPay 8B-aligned)
    int*   kgCur  = qCtr + 2;                   // 391
    int*   uCur   = kgCur + NBK;                // 391
    int*   kgPay  = uCur + NBU;                 // 2,000,000 int (idx 1568, even)
    int2*  uPay   = (int2*)(kgPay + N_EDGES);   // 2,000,000 int2 (8 B aligned)
    float* Pbuf   = (float*)(uPay + NNZ);       // 512
    float* cbuf   = Pbuf + 64 * 8;              // 8
    size_t need_bytes = (size_t)((NBK + 1) + (NBU + 1) + 2 + NBK + NBU +
                                 N_EDGES + 2 * (size_t)NNZ + 512 + 8) * 4;

    if (ws_size >= need_bytes) {
        // zero histograms + steal counter in one memset (contiguous)
        hipMemsetAsync(kgOffs, 0,
                       (size_t)((NBK + 1) + (NBU + 1) + 2) * sizeof(int), stream);

        hist_both<<<PB, 512, 0, stream>>>(head, irows, kgOffs, uOffs);
        scan_both<<<2, 512, 0, stream>>>(kgOffs, kgCur, uOffs, uCur);
        scatter_both<<<2 * PB + 1, 512, 0, stream>>>(head, tail, edge_type, kgCur, kgPay,
                                                     irows, icols, ivals, uCur, uPay,
                                                     latent_emb, weight, W_weight_att,
                                                     b_weight_att, W1, b1, W2, b2,
                                                     Pbuf, cbuf, lat_out);
        acc_both<<<ACCBLK, 1024, 0, stream>>>(kgPay, kgOffs, uPay, uOffs,
                                              entity_emb, weight, user_emb,
                                              Pbuf, cbuf, W_user_att, b_user_att,
                                              lat_out, qCtr, ent_out, user_out);
    } else {
        // ---------- fallback atomic path ----------
        float* cnt   = (float*)d_ws;
        float* Pbuf2 = cnt + N_ENTITIES;
        float* cbuf2 = Pbuf2 + 64 * 8;
        hipMemsetAsync(ent_out, 0,
                       (size_t)(N_ENTITIES + N_USERS) * EMB * sizeof(float), stream);
        hipMemsetAsync(cnt, 0, N_ENTITIES * sizeof(float), stream);
        int blocks_edges = (N_EDGES * 64) / 256;
        kg_scatter<<<blocks_edges, 256, 0, stream>>>(head, tail, edge_type, entity_emb,
                                                     weight, ent_out, cnt);
        user_scatter<<<blocks_edges, 256, 0, stream>>>(irows, icols, ivals, entity_emb,
                                                       user_out);
        small_dense<<<1, 64, 0, stream>>>(latent_emb, weight, W_weight_att,
                                          b_weight_att, W1, b1, W2, b2,
                                          Pbuf2, cbuf2, lat_out);
        user_finalize<<<(N_USERS * 64) / 256, 256, 0, stream>>>(user_emb, Pbuf2, cbuf2,
                                                                W_user_att, b_user_att,
                                                                lat_out, user_out);
        entity_div<<<(N_ENTITIES * EMB) / 256, 256, 0, stream>>>(ent_out, cnt);
    }
}